// Round 8
// baseline (89.805 us; speedup 1.0000x reference)
//
#include <hip/hip_runtime.h>

// Coords2Grid: libmolgrid-style density splat.  DIAGNOSTIC ROUND: REPS=3
// honest recomputation to lift the dispatch above the 40us poison fills so
// rocprof's top-5 table shows this kernel's counters. Math identical to R7.
#define GR    48
#define GR2   (GR * GR)
#define GR3   (GR * GR * GR)
#define NA    800
#define NT    28
#define RESF  0.5f
#define HALF_DIM 11.75f
#define INV_E2 0.13533528323661270f

#define TXC   2
#define TYC   2
#define TZC   16
#define NTX   (GR / TXC)            // 24
#define NTY   (GR / TYC)            // 24
#define NTZ   (GR / TZC)            // 3
#define NBLK  (NTX * NTY * NTZ)     // 1728
#define KB    64                    // atoms per batch
#define KPAD  80                    // ushort row stride (160B, 16B-aligned)
#define REPS  3

typedef __attribute__((ext_vector_type(8))) short short8;
typedef __attribute__((ext_vector_type(4))) float floatx4;

__device__ inline unsigned short f2bf(float x) {  // RNE float->bf16 (finite, >=0)
    unsigned u = __builtin_bit_cast(unsigned, x);
    u = (u + 0x7FFFu + ((u >> 16) & 1u)) >> 16;
    return (unsigned short)u;
}

__global__ __launch_bounds__(256) void c2g_kernel(
    const float* __restrict__ center,
    const float* __restrict__ coords,
    const float* __restrict__ types,
    const float* __restrict__ radii,
    float* __restrict__ out)
{
    __shared__ float4 s_atom[NA];              // xyz + 1/r^2
    __shared__ int    s_ai[NA];
    __shared__ int    s_cnt;
    __shared__ unsigned short s_val[64 * KPAD]; // [cell][atom] bf16
    __shared__ unsigned short s_tT[32 * KPAD];  // [type][atom] bf16
    __shared__ float  s_out[64 * 33];           // [cell][type] padded

    const int tid  = threadIdx.x;
    const int lane = tid & 63;
    const int w    = tid >> 6;
    const int b    = blockIdx.x;
    const int tz   = b % NTZ;
    const int ty   = (b / NTZ) % NTY;
    const int tx   = b / (NTZ * NTY);

    const float ox = center[0] - HALF_DIM;
    const float oy = center[1] - HALF_DIM;
    const float oz = center[2] - HALF_DIM;

    const float bxlo = ox + tx * (TXC * RESF), bxhi = bxlo + (TXC - 1) * RESF;
    const float bylo = oy + ty * (TYC * RESF), byhi = bylo + (TYC - 1) * RESF;
    const float bzlo = oz + tz * (TZC * RESF), bzhi = bzlo + (TZC - 1) * RESF;

    // Lane -> cell within 2x2x16 tile (z fastest).
    const int lzz = lane & 15;
    const int ly2 = (lane >> 4) & 1;
    const int lx2 = lane >> 5;
    const float gx = bxlo + lx2 * RESF;
    const float gy = bylo + ly2 * RESF;
    const float gz = bzlo + lzz * RESF;

    const int lm = lane & 15;     // MFMA row/col within tile
    const int lg = lane >> 4;     // MFMA k-group

    // Type-staging slots: s in {tid, tid+256}; row = s>>3 (atom), q = s&7.
    const int r0 = tid >> 3,         q0 = tid & 7;
    const int r1 = (tid + 256) >> 3, q1 = tid & 7;  // same q, rows 32..63

    for (int rep = 0; rep < REPS; ++rep) {
        __syncthreads();                 // protect s_cnt/s_out reuse across reps
        if (tid == 0) s_cnt = 0;
        __syncthreads();

        // ---- Prefilter: ballot-compacted ----
        for (int a0 = 0; a0 < NA; a0 += 256) {
            int a = a0 + tid;
            bool accept = false;
            float ax = 0.f, ay = 0.f, az = 0.f, r = 1.f;
            if (a < NA) {
                ax = coords[3 * a + 0];
                ay = coords[3 * a + 1];
                az = coords[3 * a + 2];
                r  = radii[a];
                float cut = 1.5f * r;
                float ddx = ax - fminf(fmaxf(ax, bxlo), bxhi);
                float ddy = ay - fminf(fmaxf(ay, bylo), byhi);
                float ddz = az - fminf(fmaxf(az, bzlo), bzhi);
                float d2 = fmaf(ddx, ddx, fmaf(ddy, ddy, ddz * ddz));
                accept = d2 < cut * cut;
            }
            unsigned long long m = __ballot(accept);
            if (m) {
                int base = 0;
                if (lane == 0) base = atomicAdd(&s_cnt, __popcll(m));
                base = __shfl(base, 0);
                if (accept) {
                    int p = base + __popcll(m & ((1ull << lane) - 1ull));
                    s_atom[p] = make_float4(ax, ay, az, 1.0f / (r * r));
                    s_ai[p] = a;
                }
            }
        }
        __syncthreads();
        const int cnt = s_cnt;

        floatx4 acc0 = {0.f, 0.f, 0.f, 0.f};   // types  0..15
        floatx4 acc1 = {0.f, 0.f, 0.f, 0.f};   // types 16..31 (28..31 pad)

        for (int k0 = 0; k0 < cnt; k0 += KB) {
            const int kmax = (cnt - k0 < KB) ? (cnt - k0) : KB;

            // ---- Issue type-row loads early (T14); zero-fill invalid slots ----
            float4 tv0 = make_float4(0.f, 0.f, 0.f, 0.f);
            float4 tv1 = tv0;
            if (q0 < 7 && r0 < kmax)
                tv0 = *(const float4*)(types + s_ai[k0 + r0] * NT + q0 * 4);
            if (q1 < 7 && r1 < kmax)
                tv1 = *(const float4*)(types + s_ai[k0 + r1] * NT + q1 * 4);

            // ---- Stage A: wave w computes+packs val rows [w*16, w*16+16) ----
            unsigned pk[8];
            #pragma unroll
            for (int jj = 0; jj < 8; ++jj) {
                float v[2];
                #pragma unroll
                for (int h = 0; h < 2; ++h) {
                    int row = w * 16 + 2 * jj + h;
                    float vv = 0.0f;
                    if (row < kmax) {                    // wave-uniform
                        float4 at = s_atom[k0 + row];
                        float dx = gx - at.x;
                        float dy = gy - at.y;
                        float dz = gz - at.z;
                        float d2 = fmaf(dx, dx, fmaf(dy, dy, dz * dz));
                        float dr2 = d2 * at.w;
                        float g  = __expf(-2.0f * dr2);
                        float dr = sqrtf(dr2);
                        float q  = INV_E2 * fmaf(4.0f, dr2, fmaf(-12.0f, dr, 9.0f));
                        vv = (dr2 < 1.0f) ? g : ((dr2 < 2.25f) ? q : 0.0f);
                    }
                    v[h] = vv;
                }
                pk[jj] = (unsigned)f2bf(v[0]) | ((unsigned)f2bf(v[1]) << 16);
            }
            *(uint4*)&s_val[lane * KPAD + w * 16]     = *(uint4*)&pk[0];
            *(uint4*)&s_val[lane * KPAD + w * 16 + 8] = *(uint4*)&pk[4];

            // ---- Transposed type write [type][atom]; q==7 zeros rows 28..31 ----
            {
                const float* e0 = &tv0.x;
                const float* e1 = &tv1.x;
                #pragma unroll
                for (int i = 0; i < 4; ++i) {
                    s_tT[(q0 * 4 + i) * KPAD + r0] = f2bf(e0[i]);
                    s_tT[(q1 * 4 + i) * KPAD + r1] = f2bf(e1[i]);
                }
            }
            __syncthreads();

            // ---- Stage B: MFMA — C[cell-tile w][types] += V-tile * T-tile ----
            #pragma unroll
            for (int ks = 0; ks < 2; ++ks) {
                int ko = ks * 32 + lg * 8;
                short8 afr = *(const short8*)&s_val[(w * 16 + lm) * KPAD + ko];
                short8 b0  = *(const short8*)&s_tT[lm * KPAD + ko];
                short8 b1  = *(const short8*)&s_tT[(16 + lm) * KPAD + ko];
                acc0 = __builtin_amdgcn_mfma_f32_16x16x32_bf16(afr, b0, acc0, 0, 0, 0);
                acc1 = __builtin_amdgcn_mfma_f32_16x16x32_bf16(afr, b1, acc1, 0, 0, 0);
            }
            __syncthreads();
        }

        // ---- Epilogue: acc -> LDS -> coalesced stores ----
        #pragma unroll
        for (int r = 0; r < 4; ++r) {
            int cellO = w * 16 + lg * 4 + r;
            s_out[cellO * 33 + lm]      = acc0[r];
            s_out[cellO * 33 + 16 + lm] = acc1[r];
        }
        __syncthreads();

        #pragma unroll
        for (int i = 0; i < 7; ++i) {
            int idx = i * 256 + tid;                 // < 1792 = 28*64
            int t = idx >> 6;
            int c = idx & 63;
            int z = c & 15, y = (c >> 4) & 1, x = c >> 5;
            int gidx = (tx * TXC + x) * GR2 + (ty * TYC + y) * GR + tz * TZC + z;
            out[t * GR3 + gidx] = s_out[c * 33 + t];
        }
        asm volatile("" ::: "memory");   // no cross-rep CSE
    }
}

extern "C" void kernel_launch(void* const* d_in, const int* in_sizes, int n_in,
                              void* d_out, int out_size, void* d_ws, size_t ws_size,
                              hipStream_t stream) {
    const float* center = (const float*)d_in[0];
    const float* coords = (const float*)d_in[1];
    const float* types  = (const float*)d_in[2];
    const float* radii  = (const float*)d_in[3];
    float* out = (float*)d_out;

    c2g_kernel<<<dim3(NBLK), dim3(256), 0, stream>>>(center, coords, types, radii, out);
}

// Round 9
// 74.716 us; speedup vs baseline: 1.2019x; 1.2019x over previous
//
#include <hip/hip_runtime.h>

// Coords2Grid: libmolgrid-style density splat via MFMA.
// C[type][cell] = sum_atoms T[type][atom] * V[atom][cell]
//   A = T staged transposed in LDS (double-buffered), B = V computed in-register.
// Slot-wise A/B atom agreement makes the HW k-permutation cancel (no layout
// assumption). Sentinel-padded atom list: no bounds checks in the hot loop.
#define GR    48
#define GR2   (GR * GR)
#define GR3   (GR * GR * GR)
#define NA    800
#define NAP   864                   // NA rounded to 64-multiple + pad
#define NT    28
#define RESF  0.5f
#define HALF_DIM 11.75f
#define INV_E2 0.13533528323661270f

#define TXC   2
#define TYC   2
#define TZC   16
#define NTX   (GR / TXC)            // 24
#define NTY   (GR / TYC)            // 24
#define NTZ   (GR / TZC)            // 3
#define NBLK  (NTX * NTY * NTZ)     // 1728
#define KB    64                    // atoms per batch
#define KPAD  80                    // ushort stride per type row (16B-aligned)
#define TBUF  (32 * KPAD)           // ushorts per tT buffer

typedef __attribute__((ext_vector_type(8))) short short8;
typedef __attribute__((ext_vector_type(4))) float floatx4;

__device__ inline unsigned short f2bf(float x) {  // RNE float->bf16 (finite, >=0)
    unsigned u = __builtin_bit_cast(unsigned, x);
    u = (u + 0x7FFFu + ((u >> 16) & 1u)) >> 16;
    return (unsigned short)u;
}

__global__ __launch_bounds__(256) void c2g_kernel(
    const float* __restrict__ center,
    const float* __restrict__ coords,
    const float* __restrict__ types,
    const float* __restrict__ radii,
    float* __restrict__ out)
{
    // LDS carve-out: s_atom | s_ai | s_tT[2]; s_out aliases s_atom (dead by epilogue).
    __shared__ __align__(16) unsigned char smem[NAP * 16 + NAP * 4 + 2 * TBUF * 2];
    float4*         s_atom = (float4*)smem;                          // [NAP]
    int*            s_ai   = (int*)(smem + NAP * 16);                // [NAP]
    unsigned short* s_tT   = (unsigned short*)(smem + NAP * 20);     // [2][TBUF]
    float*          s_out  = (float*)smem;                           // [64*33]
    __shared__ int s_cnt;

    const int tid  = threadIdx.x;
    const int lane = tid & 63;
    const int w    = tid >> 6;
    const int b    = blockIdx.x;
    const int tz   = b % NTZ;
    const int ty   = (b / NTZ) % NTY;
    const int tx   = b / (NTZ * NTY);

    const float ox = center[0] - HALF_DIM;
    const float oy = center[1] - HALF_DIM;
    const float oz = center[2] - HALF_DIM;

    const float bxlo = ox + tx * (TXC * RESF), bxhi = bxlo + (TXC - 1) * RESF;
    const float bylo = oy + ty * (TYC * RESF), byhi = bylo + (TYC - 1) * RESF;
    const float bzlo = oz + tz * (TZC * RESF), bzhi = bzlo + (TZC - 1) * RESF;

    if (tid == 0) s_cnt = 0;
    __syncthreads();

    // ---- Prefilter: ballot-compacted ----
    for (int a0 = 0; a0 < NA; a0 += 256) {
        int a = a0 + tid;
        bool accept = false;
        float ax = 0.f, ay = 0.f, az = 0.f, r = 1.f;
        if (a < NA) {
            ax = coords[3 * a + 0];
            ay = coords[3 * a + 1];
            az = coords[3 * a + 2];
            r  = radii[a];
            float cut = 1.5f * r;
            float ddx = ax - fminf(fmaxf(ax, bxlo), bxhi);
            float ddy = ay - fminf(fmaxf(ay, bylo), byhi);
            float ddz = az - fminf(fmaxf(az, bzlo), bzhi);
            float d2 = fmaf(ddx, ddx, fmaf(ddy, ddy, ddz * ddz));
            accept = d2 < cut * cut;
        }
        unsigned long long m = __ballot(accept);
        if (m) {
            int base = 0;
            if (lane == 0) base = atomicAdd(&s_cnt, __popcll(m));
            base = __shfl(base, 0);
            if (accept) {
                int p = base + __popcll(m & ((1ull << lane) - 1ull));
                s_atom[p] = make_float4(ax, ay, az, 1.0f / (r * r));
                s_ai[p] = a;
            }
        }
    }
    __syncthreads();
    const int cnt  = s_cnt;
    const int cntp = (cnt + 63) & ~63;
    const int nb   = cntp >> 6;

    // ---- Sentinel pad: far-away atoms -> val 0, type row 0 (harmless x0) ----
    for (int i = cnt + tid; i < cntp; i += 256) {
        s_atom[i] = make_float4(1e9f, 1e9f, 1e9f, 1.0f);
        s_ai[i] = 0;
    }
    __syncthreads();

    // Lane roles. B-frag col = cell = w*16 + lm  (z = lm, y = w&1, x = w>>1).
    const int lm = lane & 15;
    const int lg = lane >> 4;
    const float gx = bxlo + (w >> 1) * RESF;
    const float gy = bylo + (w & 1) * RESF;
    const float gz = bzlo + lm * RESF;

    // Type staging slots: (atom row rr, float4 slot qq); qq==7 writes zeros
    // into pad types 28..31.
    const int r0 = tid >> 3, q0 = tid & 7;
    const int r1 = r0 + 32;

    auto evalv = [&](int idx) -> float {
        float4 at = s_atom[idx];
        float dx = gx - at.x, dy = gy - at.y, dz = gz - at.z;
        float d2 = fmaf(dx, dx, fmaf(dy, dy, dz * dz));
        float dr2 = d2 * at.w;
        float g  = __expf(-2.0f * dr2);
        float dr = sqrtf(dr2);
        float qd = INV_E2 * fmaf(4.0f, dr2, fmaf(-12.0f, dr, 9.0f));
        return (dr2 < 1.0f) ? g : ((dr2 < 2.25f) ? qd : 0.0f);
    };
    auto pk2 = [&](int idx) -> unsigned {   // pack vals (idx, idx+1) -> bf16x2
        float a = evalv(idx), bsc = evalv(idx + 1);
        return (unsigned)f2bf(a) | ((unsigned)f2bf(bsc) << 16);
    };
    auto stage = [&](unsigned short* tb, float4 tv, int rr, int qq) {
        tb[(qq * 4 + 0) * KPAD + rr] = f2bf(tv.x);
        tb[(qq * 4 + 1) * KPAD + rr] = f2bf(tv.y);
        tb[(qq * 4 + 2) * KPAD + rr] = f2bf(tv.z);
        tb[(qq * 4 + 3) * KPAD + rr] = f2bf(tv.w);
    };

    floatx4 acc0 = {0.f, 0.f, 0.f, 0.f};   // types  0..15 (rows), cell col lm
    floatx4 acc1 = {0.f, 0.f, 0.f, 0.f};   // types 16..31

    // ---- Prologue: stage batch 0 into buffer 0 ----
    if (nb > 0) {
        float4 t0 = make_float4(0.f, 0.f, 0.f, 0.f), t1 = t0;
        if (q0 < 7) {
            t0 = *(const float4*)(types + s_ai[r0] * NT + q0 * 4);
            t1 = *(const float4*)(types + s_ai[r1] * NT + q0 * 4);
        }
        stage(s_tT, t0, r0, q0);
        stage(s_tT, t1, r1, q0);
    }
    __syncthreads();

    // ---- Main loop: 1 barrier per batch ----
    for (int bi = 0; bi < nb; ++bi) {
        const int k0  = bi * KB;
        const int cur = bi & 1;
        const unsigned short* tb = s_tT + cur * TBUF;
        unsigned short* tbn = s_tT + (cur ^ 1) * TBUF;

        // 1. Issue next batch's type loads early (hidden under evals).
        float4 t0 = make_float4(0.f, 0.f, 0.f, 0.f), t1 = t0;
        const bool have_next = (bi + 1 < nb);
        if (have_next && q0 < 7) {
            t0 = *(const float4*)(types + s_ai[k0 + KB + r0] * NT + q0 * 4);
            t1 = *(const float4*)(types + s_ai[k0 + KB + r1] * NT + q0 * 4);
        }

        // 2. Compute B-fragments in-register (slot j = atom k0 + kt*32 + lg*8 + j).
        const int base0 = k0 + lg * 8;
        const int base1 = k0 + 32 + lg * 8;
        short8 bf0 = __builtin_bit_cast(short8,
            make_uint4(pk2(base0), pk2(base0 + 2), pk2(base0 + 4), pk2(base0 + 6)));
        short8 bf1 = __builtin_bit_cast(short8,
            make_uint4(pk2(base1), pk2(base1 + 2), pk2(base1 + 4), pk2(base1 + 6)));

        // 3. MFMA: A rows = types (from s_tT, k-contiguous -> slot j = same atom).
        short8 a00 = *(const short8*)&tb[lm * KPAD + lg * 8];
        short8 a10 = *(const short8*)&tb[(16 + lm) * KPAD + lg * 8];
        acc0 = __builtin_amdgcn_mfma_f32_16x16x32_bf16(a00, bf0, acc0, 0, 0, 0);
        acc1 = __builtin_amdgcn_mfma_f32_16x16x32_bf16(a10, bf0, acc1, 0, 0, 0);
        short8 a01 = *(const short8*)&tb[lm * KPAD + 32 + lg * 8];
        short8 a11 = *(const short8*)&tb[(16 + lm) * KPAD + 32 + lg * 8];
        acc0 = __builtin_amdgcn_mfma_f32_16x16x32_bf16(a01, bf1, acc0, 0, 0, 0);
        acc1 = __builtin_amdgcn_mfma_f32_16x16x32_bf16(a11, bf1, acc1, 0, 0, 0);

        // 4. Write next batch's staged types; 5. one barrier.
        if (have_next) {
            stage(tbn, t0, r0, q0);
            stage(tbn, t1, r1, q0);
        }
        __syncthreads();
    }

    // ---- Epilogue: acc -> s_out (aliases dead s_atom) -> coalesced stores ----
    #pragma unroll
    for (int r = 0; r < 4; ++r) {
        int c = w * 16 + lm;
        s_out[c * 33 + lg * 4 + r]      = acc0[r];
        s_out[c * 33 + 16 + lg * 4 + r] = acc1[r];
    }
    __syncthreads();

    #pragma unroll
    for (int i = 0; i < 7; ++i) {
        int idx = i * 256 + tid;                 // < 1792 = 28*64
        int t = idx >> 6;
        int c = idx & 63;
        int z = c & 15, y = (c >> 4) & 1, x = c >> 5;
        int gidx = (tx * TXC + x) * GR2 + (ty * TYC + y) * GR + tz * TZC + z;
        out[t * GR3 + gidx] = s_out[c * 33 + t];
    }
}

extern "C" void kernel_launch(void* const* d_in, const int* in_sizes, int n_in,
                              void* d_out, int out_size, void* d_ws, size_t ws_size,
                              hipStream_t stream) {
    const float* center = (const float*)d_in[0];
    const float* coords = (const float*)d_in[1];
    const float* types  = (const float*)d_in[2];
    const float* radii  = (const float*)d_in[3];
    float* out = (float*)d_out;

    c2g_kernel<<<dim3(NBLK), dim3(256), 0, stream>>>(center, coords, types, radii, out);
}